// Round 6
// baseline (618.845 us; speedup 1.0000x reference)
//
#include <hip/hip_runtime.h>
#include <hip/hip_bf16.h>
#include <stdint.h>

typedef __attribute__((ext_vector_type(8))) short short8;
typedef __attribute__((ext_vector_type(8))) unsigned short ushort8;
typedef __attribute__((ext_vector_type(16))) float f32x16;
typedef __attribute__((ext_vector_type(8))) __bf16 bf16x8;

#define GAS __attribute__((address_space(1)))
#define LAS __attribute__((address_space(3)))

static constexpr int Bn = 16384;   // batch
static constexpr int Hn = 1024;    // hidden
static constexpr int KT = 4096;    // IN + H + CTX (concat K)
static constexpr int NT = KT / 64; // 64 K-tiles (even)

#define SBAR()   __builtin_amdgcn_s_barrier()
#define VMCNT(n) asm volatile("s_waitcnt vmcnt(" #n ")" ::: "memory")

__device__ __forceinline__ unsigned short f2bf(float f) {
  unsigned u = __builtin_bit_cast(unsigned, f);
  u = (u + 0x7FFFu + ((u >> 16) & 1u)) >> 16;   // RNE
  return (unsigned short)u;
}

__device__ __forceinline__ float fast_sigm(float x) {
  return __builtin_amdgcn_rcpf(1.f + __expf(-x));
}
__device__ __forceinline__ float fast_tanh(float x) {
  return 1.f - 2.f * __builtin_amdgcn_rcpf(__expf(2.f * x) + 1.f);
}

// Concat-convert 3 fp32 sources (widths 1024,1024,2048) into bf16 [rows][4096].
__global__ __launch_bounds__(256) void cvt_concat_k(
    const float* __restrict__ s0, const float* __restrict__ s1,
    const float* __restrict__ s2, unsigned short* __restrict__ dst,
    long long n8) {
  long long stride = (long long)gridDim.x * blockDim.x;
  for (long long g = (long long)blockIdx.x * blockDim.x + threadIdx.x; g < n8;
       g += stride) {
    long long row = g >> 9;
    int cg = (int)(g & 511) << 3;
    const float* src;
    if (cg < 1024)      src = s0 + row * 1024 + cg;
    else if (cg < 2048) src = s1 + row * 1024 + (cg - 1024);
    else                src = s2 + row * 2048 + (cg - 2048);
    float4 f0 = *(const float4*)src;
    float4 f1 = *(const float4*)(src + 4);
    ushort8 o;
    o[0] = f2bf(f0.x); o[1] = f2bf(f0.y); o[2] = f2bf(f0.z); o[3] = f2bf(f0.w);
    o[4] = f2bf(f1.x); o[5] = f2bf(f1.y); o[6] = f2bf(f1.z); o[7] = f2bf(f1.w);
    *(ushort8*)(dst + (g << 3)) = o;
  }
}

// 256x256 GEMM + fused LSTM on mfma_f32_32x32x16_bf16 (2495 TF pipe, half the
// MFMA instruction count of 16x16x32). 8 waves as 4M x 2N: wave = 64 rows x
// 128 cols = 2 rf x 4 cf frags; cf == GATE (B rows gate-interleaved) so all 4
// gates per output stay in one lane -> fused epilogue.
// 4 phases/K-tile (rf,kh), one-phase-ahead reads (2,10,2,10), 5 barriers/tile,
// double-buffered 128KB LDS, st_16x32 both-sides swizzle, counted-vmcnt:
//   stages: ph0(t): {A-lo,A-hi,B-hi}(t+1)->buf p^1 ; ph3(t): B-lo(t+2)->buf p
//   gate:   ph3(t): VMCNT(2) + barrier (retires ph0's 6; B-lo(t+2) in flight)
// Audited: every stage lands after [consuming reads' MFMA-retire + barrier];
// every cross-wave read follows [own-wave gate -> barrier]; never vmcnt(0).
__global__ __launch_bounds__(512, 2) void lstm_gemm(
    const unsigned short* __restrict__ X, const unsigned short* __restrict__ Wc,
    const float* __restrict__ bias, const float* __restrict__ c0,
    float* __restrict__ out_c, float* __restrict__ out_h) {
  extern __shared__ char smem[];  // 131072 B: [2 bufs][A 32KB | B 32KB]

  int bid = blockIdx.x;
  int swz = (bid & 7) * 128 + (bid >> 3);  // 1024 blocks, 8 XCDs, bijective
  int mblk = swz >> 4, cblk = swz & 15;    // 16 consecutive share A-panel
  int brow0 = mblk * 256;
  int hcol0 = cblk * 64;

  int tid = threadIdx.x;
  int lane = tid & 63, wid = tid >> 6;
  int wr = wid >> 1, wc = wid & 1;  // 4M x 2N wave grid

  const char* Xc = (const char*)X;
  const char* Wcc = (const char*)Wc;

  // ---- staging source offsets (inverse-swizzled global, linear LDS dest) ----
  int rr = tid >> 3;                                        // 0..63
  uint32_t cbyte = (uint32_t)(((tid & 7) * 16) ^ ((rr & 7) << 4));
  uint32_t aoff[2][2], boff[2][2];
#pragma unroll
  for (int half = 0; half < 2; ++half) {
#pragma unroll
    for (int j = 0; j < 2; ++j) {
      int r = half * 128 + j * 64 + rr;                     // tile row 0..255
      aoff[half][j] = (uint32_t)(brow0 + r) * (KT * 2) + cbyte;
      // B-row r -> W row: gate=(r>>5)&3, hcol = hcol0 + (r>>7)*32 + (r&31)
      int w = ((r >> 5) & 3) * 1024 + hcol0 + ((r >> 7) << 5) + (r & 31);
      boff[half][j] = (uint32_t)w * (KT * 2) + cbyte;
    }
  }

  auto stage_half = [&](int isB, int half, int tt) {
    int ts = tt < NT ? tt : NT - 1;
    int bufs = tt & 1;
#pragma unroll
    for (int j = 0; j < 2; ++j) {
      uint32_t off = (isB ? boff[half][j] : aoff[half][j]) + (uint32_t)ts * 128u;
      const char* src = (isB ? Wcc : Xc) + off;
      char* dst = smem + bufs * 65536 + isB * 32768 + half * 16384 + j * 8192 +
                  wid * 1024;
      __builtin_amdgcn_global_load_lds((const GAS unsigned int*)src,
                                       (LAS unsigned int*)dst, 16, 0, 0);
    }
  };

  // ---- ds_read addressing (32x32 operand layout: row=lane&31, k-half=lane>>5)
  int l31 = lane & 31;
  int sw = (lane & 7) << 4;
  int kb = (lane >> 5) << 4;  // 0 or 16 bytes (k 0..7 / 8..15 of the k-step)
  int k_[4];
#pragma unroll
  for (int ks = 0; ks < 4; ++ks) k_[ks] = (ks * 32 + kb) ^ sw;
  uint32_t abase = (uint32_t)(wr * 64 + l31) * 128;            // + rf*4096 + k
  uint32_t bbase = 32768u + (uint32_t)(wc * 128 + l31) * 128;  // + cf*4096 + k

#define LDA(PB, RF, KOFF) \
  *(const short8*)(smem + (PB) + abase + (RF) * 4096 + (KOFF))
#define LDB(PB, CF, KOFF) \
  *(const short8*)(smem + (PB) + bbase + (CF) * 4096 + (KOFF))

  f32x16 acc[2][4] = {};   // [rf][cf=gate]
  short8 areg[2][2];       // [phase parity][ks in k-half]
  short8 bfr[4][4];        // [cf][ks]

  // ---- prologue: tile0 full + B-lo(1) (10 loads) ----
  stage_half(0, 0, 0);   // A-lo(0)
  stage_half(0, 1, 0);   // A-hi(0)
  stage_half(1, 0, 0);   // B-lo(0)
  stage_half(1, 1, 0);   // B-hi(0)
  stage_half(1, 0, 1);   // B-lo(1) -> buf 1
  VMCNT(2);              // tile 0 landed; B-lo(1) in flight
  SBAR();
  {  // emulate ph3(-1) reads: B(0) kh0 + A rf0 kh0
#pragma unroll
    for (int cf = 0; cf < 4; ++cf) {
      bfr[cf][0] = LDB(0, cf, k_[0]);
      bfr[cf][1] = LDB(0, cf, k_[1]);
    }
    areg[0][0] = LDA(0, 0, k_[0]);
    areg[0][1] = LDA(0, 0, k_[1]);
  }

#define MFMA8(RF, KH, PAR)                                                    \
  __builtin_amdgcn_s_setprio(1);                                              \
  _Pragma("unroll")                                                           \
  for (int cf = 0; cf < 4; ++cf)                                              \
    acc[RF][cf] = __builtin_amdgcn_mfma_f32_32x32x16_bf16(                    \
        __builtin_bit_cast(bf16x8, areg[PAR][0]),                             \
        __builtin_bit_cast(bf16x8, bfr[cf][2 * (KH)]), acc[RF][cf], 0, 0, 0); \
  _Pragma("unroll")                                                           \
  for (int cf = 0; cf < 4; ++cf)                                              \
    acc[RF][cf] = __builtin_amdgcn_mfma_f32_32x32x16_bf16(                    \
        __builtin_bit_cast(bf16x8, areg[PAR][1]),                             \
        __builtin_bit_cast(bf16x8, bfr[cf][2 * (KH) + 1]), acc[RF][cf], 0, 0, \
        0);                                                                   \
  __builtin_amdgcn_s_setprio(0);

  for (int t = 0; t < NT; ++t) {
    int pb = (t & 1) * 65536;
    int qb = pb ^ 65536;
    // ---- ph0: MFMA(rf0,kh0); stage A(t+1)+B-hi(t+1); read A rf1 kh0 ----
    stage_half(0, 0, t + 1);
    stage_half(0, 1, t + 1);
    stage_half(1, 1, t + 1);
    areg[1][0] = LDA(pb, 1, k_[0]);
    areg[1][1] = LDA(pb, 1, k_[1]);
    MFMA8(0, 0, 0)
    SBAR();
    // ---- ph1: MFMA(rf1,kh0); read A rf0 kh1 + B(t) kh1 ----
    areg[0][0] = LDA(pb, 0, k_[2]);
    areg[0][1] = LDA(pb, 0, k_[3]);
#pragma unroll
    for (int cf = 0; cf < 4; ++cf) {
      bfr[cf][2] = LDB(pb, cf, k_[2]);
      bfr[cf][3] = LDB(pb, cf, k_[3]);
    }
    MFMA8(1, 0, 1)
    SBAR();
    // ---- ph2: MFMA(rf0,kh1); read A rf1 kh1 ----
    areg[1][0] = LDA(pb, 1, k_[2]);
    areg[1][1] = LDA(pb, 1, k_[3]);
    MFMA8(0, 1, 0)
    SBAR();
    // ---- ph3: stage B-lo(t+2); gate; read next-tile B kh0 + A rf0 kh0;
    //           MFMA(rf1,kh1) ----
    stage_half(1, 0, t + 2);
    VMCNT(2);
    SBAR();  // gate barrier: all waves' ph0 stages retired -> buf p^1 readable
#pragma unroll
    for (int cf = 0; cf < 4; ++cf) {
      bfr[cf][0] = LDB(qb, cf, k_[0]);
      bfr[cf][1] = LDB(qb, cf, k_[1]);
    }
    areg[0][0] = LDA(qb, 0, k_[0]);
    areg[0][1] = LDA(qb, 0, k_[1]);
    MFMA8(1, 1, 1)
    SBAR();
  }
#undef MFMA8
#undef LDA
#undef LDB

  // ---- fused LSTM epilogue ----
  // C/D 32x32 map: col = lane&31, row = (reg&3) + 8*(reg>>2) + 4*(lane>>5)
  int col = hcol0 + wc * 32 + l31;
  float bi = bias[col], bf_ = bias[1024 + col];
  float bo = bias[2048 + col], bc = bias[3072 + col];
#pragma unroll
  for (int rf = 0; rf < 2; ++rf) {
    int rbase = brow0 + wr * 64 + rf * 32 + ((lane >> 5) << 2);
#pragma unroll
    for (int reg = 0; reg < 16; ++reg) {
      int grow = rbase + (reg & 3) + ((reg >> 2) << 3);
      size_t idx = (size_t)grow * 1024 + col;
      float i_ = fast_sigm(acc[rf][0][reg] + bi);
      float f_ = fast_sigm(acc[rf][1][reg] + bf_);
      float o_ = fast_sigm(acc[rf][2][reg] + bo);
      float ch = fast_tanh(acc[rf][3][reg] + bc);
      float cn = i_ * ch + f_ * c0[idx];
      out_c[idx] = cn;
      out_h[idx] = o_ * fast_tanh(cn);
    }
  }
}

// Fallback if ws too small (not expected; ws >= 160MB confirmed in round 1).
__global__ __launch_bounds__(256) void lstm_naive(
    const float* __restrict__ y, const float* __restrict__ ctx,
    const float* __restrict__ c0, const float* __restrict__ h0,
    const float* __restrict__ W, const float* __restrict__ U,
    const float* __restrict__ C, const float* __restrict__ b,
    float* __restrict__ out_c, float* __restrict__ out_h) {
  size_t t = (size_t)blockIdx.x * blockDim.x + threadIdx.x;
  if (t >= (size_t)Bn * Hn) return;
  int row = (int)(t >> 10), col = (int)(t & 1023);
  float g[4];
#pragma unroll
  for (int gg = 0; gg < 4; ++gg) {
    int wrow = gg * 1024 + col;
    float s = b[wrow];
    const float* yr = y + (size_t)row * 1024;
    const float* Wr = W + (size_t)wrow * 1024;
    for (int k = 0; k < 1024; ++k) s += yr[k] * Wr[k];
    const float* hr = h0 + (size_t)row * 1024;
    const float* Ur = U + (size_t)wrow * 1024;
    for (int k = 0; k < 1024; ++k) s += hr[k] * Ur[k];
    const float* cr = ctx + (size_t)row * 2048;
    const float* Cr = C + (size_t)wrow * 2048;
    for (int k = 0; k < 2048; ++k) s += cr[k] * Cr[k];
    g[gg] = s;
  }
  float i_ = fast_sigm(g[0]), f_ = fast_sigm(g[1]);
  float o_ = fast_sigm(g[2]), ch = fast_tanh(g[3]);
  float cn = i_ * ch + f_ * c0[t];
  out_c[t] = cn;
  out_h[t] = o_ * fast_tanh(cn);
}

extern "C" void kernel_launch(void* const* d_in, const int* in_sizes, int n_in,
                              void* d_out, int out_size, void* d_ws, size_t ws_size,
                              hipStream_t stream) {
  const float* y   = (const float*)d_in[0];
  const float* ctx = (const float*)d_in[1];
  const float* c0  = (const float*)d_in[2];
  const float* h0  = (const float*)d_in[3];
  const float* W   = (const float*)d_in[4];
  const float* U   = (const float*)d_in[5];
  const float* C   = (const float*)d_in[6];
  const float* b   = (const float*)d_in[7];
  float* out = (float*)d_out;
  float* out_c = out;
  float* out_h = out + (size_t)Bn * Hn;

  const size_t needX = (size_t)Bn * KT * 2;
  const size_t needW = (size_t)(4 * Hn) * KT * 2;

  if (ws_size >= needX + needW) {
    unsigned short* Xb = (unsigned short*)d_ws;
    unsigned short* Wb = (unsigned short*)((char*)d_ws + needX);
    cvt_concat_k<<<2048, 256, 0, stream>>>(y, h0, ctx, Xb, (long long)Bn * 512);
    cvt_concat_k<<<2048, 256, 0, stream>>>(W, U, C, Wb, (long long)(4 * Hn) * 512);
    (void)hipFuncSetAttribute((const void*)lstm_gemm,
                              hipFuncAttributeMaxDynamicSharedMemorySize, 131072);
    lstm_gemm<<<1024, 512, 131072, stream>>>(Xb, Wb, b, c0, out_c, out_h);
  } else {
    lstm_naive<<<(Bn * Hn + 255) / 256, 256, 0, stream>>>(y, ctx, c0, h0, W, U, C,
                                                          b, out_c, out_h);
  }
}